// Round 1
// baseline (176.884 us; speedup 1.0000x reference)
//
#include <hip/hip_runtime.h>
#include <hip/hip_bf16.h>
#include <cstdint>

#define B_    2
#define C_    256
#define H_    64
#define W_    64
#define P_    (H_*W_)      // 4096
#define N_    4
#define RAD   4
#define K2_   81
#define CTOT  (4*K2_)      // 324

typedef __bf16 bf16x8 __attribute__((ext_vector_type(8)));
typedef float  f32x4  __attribute__((ext_vector_type(4)));

__device__ __forceinline__ void gload_lds16(const void* g, void* l) {
    __builtin_amdgcn_global_load_lds(
        (const __attribute__((address_space(1))) void*)g,
        (__attribute__((address_space(3))) void*)l,
        16, 0, 0);
}

// ---------------------------------------------------------------------------
// Transpose + convert: in (B, C, P) fp32  ->  out (B, P, C) bf16
// ---------------------------------------------------------------------------
__global__ void transpose_cvt(const float* __restrict__ in,
                              __hip_bfloat16* __restrict__ out) {
    __shared__ float tile[32][33];
    const int b  = blockIdx.z;
    const int p0 = blockIdx.x * 32;
    const int c0 = blockIdx.y * 32;
    const int tx = threadIdx.x;   // 0..31
    const int ty = threadIdx.y;   // 0..7
    const float* src = in + ((size_t)b * C_ + c0) * P_ + p0;
    #pragma unroll
    for (int i = 0; i < 32; i += 8)
        tile[ty + i][tx] = src[(size_t)(ty + i) * P_ + tx];   // tile[c][p]
    __syncthreads();
    __hip_bfloat16* dst = out + ((size_t)b * P_ + p0) * C_ + c0;
    #pragma unroll
    for (int i = 0; i < 32; i += 8)
        dst[(size_t)(ty + i) * C_ + tx] = __float2bfloat16(tile[tx][ty + i]);
}

// ---------------------------------------------------------------------------
// Batched GEMM:  corr0[b,p,q] = (1/16) * sum_c f1t[b,p,c] * f2t[b,q,c]
// 128x128 tile, BK=64, 4 waves (each 64x64), 16x16x32 bf16 MFMA.
// LDS staged via global_load_lds(16B) with XOR swizzle: physical chunk pos
// = logical_chunk ^ (row & 7)  -> conflict-free ds_read_b128 fragments.
// ---------------------------------------------------------------------------
__global__ __launch_bounds__(256) void gemm_corr(
    const short* __restrict__ f1t,   // (B, 4096, 256) bf16 bits
    const short* __restrict__ f2t,   // (B, 4096, 256) bf16 bits
    __hip_bfloat16* __restrict__ corr0)  // (B, 4096, 4096) bf16
{
    __shared__ short As[128 * 64];
    __shared__ short Bs[128 * 64];

    const int tid  = threadIdx.x;
    const int lane = tid & 63;
    const int wv   = tid >> 6;
    const int wm   = (wv >> 1) * 64;
    const int wn   = (wv & 1) * 64;
    const int b    = blockIdx.z;
    const int m0   = blockIdx.y * 128;
    const int n0   = blockIdx.x * 128;
    const int qd   = lane >> 4;
    const int l15  = lane & 15;

    // staging: 1024 16B-chunks per operand per K-iter; chunk ci = it*256 + tid
    const short* gA[4];
    const short* gB[4];
    int ldsOff[4];
    #pragma unroll
    for (int it = 0; it < 4; ++it) {
        const int ci = it * 256 + tid;
        const int r  = ci >> 3;          // row 0..127
        const int cp = ci & 7;           // physical chunk pos in row
        const int kc = cp ^ (r & 7);     // logical k-chunk (8 bf16 each)
        gA[it] = f1t + ((size_t)(b * P_ + m0 + r)) * C_ + kc * 8;
        gB[it] = f2t + ((size_t)(b * P_ + n0 + r)) * C_ + kc * 8;
        ldsOff[it] = (it * 256 + wv * 64) * 8;   // wave-uniform base (shorts)
    }

    // fragment LDS addresses (shorts), constant across K-iters
    int aAddr[4][2], bAddr[4][2];
    #pragma unroll
    for (int i = 0; i < 4; ++i) {
        const int m = wm + i * 16 + l15;
        const int n = wn + i * 16 + l15;
        #pragma unroll
        for (int s = 0; s < 2; ++s) {
            const int lc = s * 4 + qd;               // logical chunk
            aAddr[i][s] = m * 64 + ((lc ^ (m & 7)) * 8);
            bAddr[i][s] = n * 64 + ((lc ^ (n & 7)) * 8);
        }
    }

    f32x4 zero = {0.f, 0.f, 0.f, 0.f};
    f32x4 acc[4][4];
    #pragma unroll
    for (int mi = 0; mi < 4; ++mi)
        #pragma unroll
        for (int ni = 0; ni < 4; ++ni)
            acc[mi][ni] = zero;

    for (int kt = 0; kt < 4; ++kt) {
        const int k0 = kt * 64;
        #pragma unroll
        for (int it = 0; it < 4; ++it) {
            gload_lds16(gA[it] + k0, As + ldsOff[it]);
            gload_lds16(gB[it] + k0, Bs + ldsOff[it]);
        }
        __syncthreads();
        #pragma unroll
        for (int s = 0; s < 2; ++s) {
            bf16x8 af[4], bfr[4];
            #pragma unroll
            for (int i = 0; i < 4; ++i) {
                af[i]  = *(const bf16x8*)(As + aAddr[i][s]);
                bfr[i] = *(const bf16x8*)(Bs + bAddr[i][s]);
            }
            #pragma unroll
            for (int mi = 0; mi < 4; ++mi)
                #pragma unroll
                for (int ni = 0; ni < 4; ++ni)
                    acc[mi][ni] = __builtin_amdgcn_mfma_f32_16x16x32_bf16(
                        af[mi], bfr[ni], acc[mi][ni], 0, 0, 0);
        }
        __syncthreads();
    }

    const float sc = 0.0625f;   // 1/sqrt(256)
    #pragma unroll
    for (int mi = 0; mi < 4; ++mi) {
        #pragma unroll
        for (int ni = 0; ni < 4; ++ni) {
            #pragma unroll
            for (int r = 0; r < 4; ++r) {
                const int row = m0 + wm + mi * 16 + qd * 4 + r;
                const int col = n0 + wn + ni * 16 + l15;
                corr0[((size_t)(b * P_ + row)) * P_ + col] =
                    __float2bfloat16(acc[mi][ni][r] * sc);
            }
        }
    }
}

// ---------------------------------------------------------------------------
// 2x2 average pool over trailing (h,w):  in (B*P, 2h2, 2w2) -> out (B*P, h2, w2)
// ---------------------------------------------------------------------------
__global__ void pool2(const __hip_bfloat16* __restrict__ in,
                      __hip_bfloat16* __restrict__ out,
                      int h2, int w2, int total) {
    const int idx = blockIdx.x * blockDim.x + threadIdx.x;
    if (idx >= total) return;
    const int x  = idx % w2;
    const int t  = idx / w2;
    const int y  = t % h2;
    const int bp = t / h2;
    const __hip_bfloat16* src =
        in + (size_t)bp * (4 * h2 * w2) + (size_t)(2 * y) * (2 * w2) + 2 * x;
    const float v = __bfloat162float(src[0]) + __bfloat162float(src[1]) +
                    __bfloat162float(src[2 * w2]) + __bfloat162float(src[2 * w2 + 1]);
    out[idx] = __float2bfloat16(v * 0.25f);
}

// ---------------------------------------------------------------------------
// Bilinear gather: one thread per output element.
// out flat layout: [b][n][h][w][c], c = level*81 + k2
// x = cx/scale + (k2/9 - 4), y = cy/scale + (k2%9 - 4)   (torch-faithful swap)
// ---------------------------------------------------------------------------
__global__ void gather_out(const float* __restrict__ coords,
                           const __hip_bfloat16* __restrict__ c0,
                           const __hip_bfloat16* __restrict__ c1,
                           const __hip_bfloat16* __restrict__ c2,
                           const __hip_bfloat16* __restrict__ c3,
                           float* __restrict__ out) {
    const int idx = blockIdx.x * blockDim.x + threadIdx.x;
    const int TOTAL = B_ * N_ * P_ * CTOT;
    if (idx >= TOTAL) return;

    const int c  = idx % CTOT;
    const int t  = idx / CTOT;
    const int p  = t % P_;
    const int t2 = t / P_;
    const int n  = t2 % N_;
    const int b  = t2 / N_;

    const int level = c / K2_;
    const int k2    = c - level * K2_;
    const int ki    = k2 / 9;    // added to x (torch-faithful)
    const int kj    = k2 % 9;    // added to y

    const float cx = coords[((size_t)((b * N_ + n) * 2 + 0)) * P_ + p];
    const float cy = coords[((size_t)((b * N_ + n) * 2 + 1)) * P_ + p];
    const float inv_scale = 1.0f / (float)(1 << level);

    const float x = cx * inv_scale + (float)(ki - RAD);
    const float y = cy * inv_scale + (float)(kj - RAD);

    const int hw = H_ >> level;
    const __hip_bfloat16* corr =
        (level == 0) ? c0 : (level == 1) ? c1 : (level == 2) ? c2 : c3;
    const __hip_bfloat16* row = corr + ((size_t)(b * P_ + p)) * hw * hw;

    const float x0f = floorf(x), y0f = floorf(y);
    const float wx = x - x0f, wy = y - y0f;
    const float lim = (float)(hw - 1);

    float acc = 0.f;
    #pragma unroll
    for (int dy = 0; dy < 2; ++dy) {
        const float yf = y0f + (float)dy;
        const float wyv = dy ? wy : (1.f - wy);
        const bool vy = (yf >= 0.f) && (yf <= lim);
        const int yc = (int)fminf(fmaxf(yf, 0.f), lim);
        #pragma unroll
        for (int dx = 0; dx < 2; ++dx) {
            const float xf = x0f + (float)dx;
            const float wxv = dx ? wx : (1.f - wx);
            const bool vx = (xf >= 0.f) && (xf <= lim);
            const int xc = (int)fminf(fmaxf(xf, 0.f), lim);
            if (vy && vx) {
                acc += wyv * wxv * __bfloat162float(row[yc * hw + xc]);
            }
        }
    }
    out[idx] = acc;
}

// ---------------------------------------------------------------------------
extern "C" void kernel_launch(void* const* d_in, const int* in_sizes, int n_in,
                              void* d_out, int out_size, void* d_ws, size_t ws_size,
                              hipStream_t stream) {
    const float* fmap1  = (const float*)d_in[0];
    const float* fmap2  = (const float*)d_in[1];
    const float* coords = (const float*)d_in[2];
    float* out = (float*)d_out;

    char* ws = (char*)d_ws;
    __hip_bfloat16* f1t = (__hip_bfloat16*)ws;                    //  4,194,304 B
    __hip_bfloat16* f2t = (__hip_bfloat16*)(ws + 4194304);        //  4,194,304 B
    __hip_bfloat16* c0  = (__hip_bfloat16*)(ws + 8388608);        // 67,108,864 B
    __hip_bfloat16* c1  = (__hip_bfloat16*)(ws + 75497472);       // 16,777,216 B
    __hip_bfloat16* c2  = (__hip_bfloat16*)(ws + 92274688);       //  4,194,304 B
    __hip_bfloat16* c3  = (__hip_bfloat16*)(ws + 96468992);       //  1,048,576 B

    // 1) transpose+convert fmaps to (B, P, C) bf16
    {
        dim3 grid(P_ / 32, C_ / 32, B_);
        dim3 blk(32, 8);
        transpose_cvt<<<grid, blk, 0, stream>>>(fmap1, f1t);
        transpose_cvt<<<grid, blk, 0, stream>>>(fmap2, f2t);
    }

    // 2) all-pairs correlation (level 0), scaled by 1/16, bf16 out
    {
        dim3 grid(P_ / 128, P_ / 128, B_);
        gemm_corr<<<grid, 256, 0, stream>>>((const short*)f1t, (const short*)f2t, c0);
    }

    // 3) pyramid pooling
    {
        int t1 = B_ * P_ * 32 * 32;
        pool2<<<(t1 + 255) / 256, 256, 0, stream>>>(c0, c1, 32, 32, t1);
        int t2 = B_ * P_ * 16 * 16;
        pool2<<<(t2 + 255) / 256, 256, 0, stream>>>(c1, c2, 16, 16, t2);
        int t3 = B_ * P_ * 8 * 8;
        pool2<<<(t3 + 255) / 256, 256, 0, stream>>>(c2, c3, 8, 8, t3);
    }

    // 4) bilinear gather -> output
    {
        const int total = B_ * N_ * P_ * CTOT;   // 10,616,832
        gather_out<<<(total + 255) / 256, 256, 0, stream>>>(coords, c0, c1, c2, c3, out);
    }
}

// Round 2
// 133.587 us; speedup vs baseline: 1.3241x; 1.3241x over previous
//
#include <hip/hip_runtime.h>
#include <hip/hip_bf16.h>
#include <cstdint>

#define B_    2
#define C_    256
#define H_    64
#define W_    64
#define P_    (H_*W_)      // 4096
#define N_    4
#define RAD   4
#define K2_   81
#define CTOT  (4*K2_)      // 324

typedef __bf16 bf16x8 __attribute__((ext_vector_type(8)));
typedef float  f32x4  __attribute__((ext_vector_type(4)));

__device__ __forceinline__ void gload_lds16(const void* g, void* l) {
    __builtin_amdgcn_global_load_lds(
        (const __attribute__((address_space(1))) void*)g,
        (__attribute__((address_space(3))) void*)l,
        16, 0, 0);
}

// ---------------------------------------------------------------------------
// Transpose + convert: in (B, C, P) fp32  ->  out (B, P, C) bf16
// ---------------------------------------------------------------------------
__global__ void transpose_cvt(const float* __restrict__ in,
                              __hip_bfloat16* __restrict__ out) {
    __shared__ float tile[32][33];
    const int b  = blockIdx.z;
    const int p0 = blockIdx.x * 32;
    const int c0 = blockIdx.y * 32;
    const int tx = threadIdx.x;   // 0..31
    const int ty = threadIdx.y;   // 0..7
    const float* src = in + ((size_t)b * C_ + c0) * P_ + p0;
    #pragma unroll
    for (int i = 0; i < 32; i += 8)
        tile[ty + i][tx] = src[(size_t)(ty + i) * P_ + tx];   // tile[c][p]
    __syncthreads();
    __hip_bfloat16* dst = out + ((size_t)b * P_ + p0) * C_ + c0;
    #pragma unroll
    for (int i = 0; i < 32; i += 8)
        dst[(size_t)(ty + i) * C_ + tx] = __float2bfloat16(tile[tx][ty + i]);
}

// ---------------------------------------------------------------------------
// Batched GEMM with fused level-1 pooling.
// corr0[b,p,q] = (1/16) * sum_c f1t[b,p,c] * f2t[b,q,c]    (bf16 out)
// Tile 128x128, BK=64, 4 waves. Cols n0..n0+127 = q-image rows {2bx, 2bx+1}
// (full 64-wide each), so each block owns aligned 2x2 pool groups and also
// emits corr1[b,p, bx*32 + 0..31] for its 128 rows.
// Epilogue: acc -> LDS bf16 tile (stride 136 shorts, 16B-aligned rows) ->
//   vectorized corr0 stores + pooled corr1 stores.
// ---------------------------------------------------------------------------
#define TSTR 136   // tile stride in shorts (272 B = 17*16 -> 16B-aligned rows)

__global__ __launch_bounds__(256) void gemm_corr(
    const short* __restrict__ f1t,   // (B, 4096, 256) bf16 bits
    const short* __restrict__ f2t,   // (B, 4096, 256) bf16 bits
    __hip_bfloat16* __restrict__ corr0,  // (B, 4096, 64, 64) bf16
    __hip_bfloat16* __restrict__ corr1)  // (B, 4096, 32, 32) bf16
{
    // staging (32 KB) and epilogue tile (34,816 B) share this buffer
    __shared__ short smem[128 * TSTR];   // 17408 shorts
    short* As = smem;                    // 128*64
    short* Bs = smem + 8192;             // 128*64

    const int tid  = threadIdx.x;
    const int lane = tid & 63;
    const int wv   = tid >> 6;
    const int wm   = (wv >> 1) * 64;
    const int wn   = (wv & 1) * 64;
    const int b    = blockIdx.z;
    const int bx   = blockIdx.x;
    const int m0   = blockIdx.y * 128;
    const int n0   = bx * 128;
    const int qd   = lane >> 4;
    const int l15  = lane & 15;

    // staging: 1024 16B-chunks per operand per K-iter; chunk ci = it*256 + tid
    const short* gA[4];
    const short* gB[4];
    int ldsOff[4];
    #pragma unroll
    for (int it = 0; it < 4; ++it) {
        const int ci = it * 256 + tid;
        const int r  = ci >> 3;          // row 0..127
        const int cp = ci & 7;           // physical chunk pos in row
        const int kc = cp ^ (r & 7);     // logical k-chunk (8 bf16 each)
        gA[it] = f1t + ((size_t)(b * P_ + m0 + r)) * C_ + kc * 8;
        gB[it] = f2t + ((size_t)(b * P_ + n0 + r)) * C_ + kc * 8;
        ldsOff[it] = (it * 256 + wv * 64) * 8;   // wave-uniform base (shorts)
    }

    // fragment LDS addresses (shorts), constant across K-iters
    int aAddr[4][2], bAddr[4][2];
    #pragma unroll
    for (int i = 0; i < 4; ++i) {
        const int m = wm + i * 16 + l15;
        const int n = wn + i * 16 + l15;
        #pragma unroll
        for (int s = 0; s < 2; ++s) {
            const int lc = s * 4 + qd;               // logical chunk
            aAddr[i][s] = m * 64 + ((lc ^ (m & 7)) * 8);
            bAddr[i][s] = n * 64 + ((lc ^ (n & 7)) * 8);
        }
    }

    f32x4 zero = {0.f, 0.f, 0.f, 0.f};
    f32x4 acc[4][4];
    #pragma unroll
    for (int mi = 0; mi < 4; ++mi)
        #pragma unroll
        for (int ni = 0; ni < 4; ++ni)
            acc[mi][ni] = zero;

    for (int kt = 0; kt < 4; ++kt) {
        const int k0 = kt * 64;
        #pragma unroll
        for (int it = 0; it < 4; ++it) {
            gload_lds16(gA[it] + k0, As + ldsOff[it]);
            gload_lds16(gB[it] + k0, Bs + ldsOff[it]);
        }
        __syncthreads();
        #pragma unroll
        for (int s = 0; s < 2; ++s) {
            bf16x8 af[4], bfr[4];
            #pragma unroll
            for (int i = 0; i < 4; ++i) {
                af[i]  = *(const bf16x8*)(As + aAddr[i][s]);
                bfr[i] = *(const bf16x8*)(Bs + bAddr[i][s]);
            }
            #pragma unroll
            for (int mi = 0; mi < 4; ++mi)
                #pragma unroll
                for (int ni = 0; ni < 4; ++ni)
                    acc[mi][ni] = __builtin_amdgcn_mfma_f32_16x16x32_bf16(
                        af[mi], bfr[ni], acc[mi][ni], 0, 0, 0);
        }
        __syncthreads();
    }

    // ---- epilogue: acc -> LDS bf16 tile (scaled) ----
    const float sc = 0.0625f;   // 1/sqrt(256)
    __hip_bfloat16* tile = (__hip_bfloat16*)smem;
    #pragma unroll
    for (int mi = 0; mi < 4; ++mi) {
        #pragma unroll
        for (int ni = 0; ni < 4; ++ni) {
            #pragma unroll
            for (int r = 0; r < 4; ++r) {
                const int rl = wm + mi * 16 + qd * 4 + r;
                const int cl = wn + ni * 16 + l15;
                tile[rl * TSTR + cl] = __float2bfloat16(acc[mi][ni][r] * sc);
            }
        }
    }
    __syncthreads();

    // ---- corr0 global write: 2048 16B-chunks, 8 per thread ----
    #pragma unroll
    for (int i = 0; i < 8; ++i) {
        const int cid = i * 256 + tid;
        const int tr  = cid >> 4;       // row 0..127
        const int tc  = cid & 15;       // 16B chunk 0..15
        const float4 v = *(const float4*)(smem + tr * TSTR + tc * 8);
        *(float4*)(corr0 + ((size_t)(b * P_ + m0 + tr)) * P_ + n0 + tc * 8) = v;
    }

    // ---- fused pool1: 128 rows x 32 pooled cols ----
    #pragma unroll
    for (int i = 0; i < 16; ++i) {
        const int oid = i * 256 + tid;
        const int pr  = oid >> 5;       // row 0..127
        const int pc  = oid & 31;       // pooled col 0..31
        const uint32_t u0 = *(const uint32_t*)(smem + pr * TSTR + 2 * pc);
        const uint32_t u1 = *(const uint32_t*)(smem + pr * TSTR + 64 + 2 * pc);
        const float a0 = __uint_as_float(u0 << 16);
        const float a1 = __uint_as_float(u0 & 0xffff0000u);
        const float b0 = __uint_as_float(u1 << 16);
        const float b1 = __uint_as_float(u1 & 0xffff0000u);
        corr1[((size_t)(b * P_ + m0 + pr)) * 1024 + bx * 32 + pc] =
            __float2bfloat16((a0 + a1 + b0 + b1) * 0.25f);
    }
}

// ---------------------------------------------------------------------------
// Fused pool2+pool3: one block per (b,p). c1 (32x32) -> c2 (16x16) -> c3 (8x8)
// ---------------------------------------------------------------------------
__global__ __launch_bounds__(256) void pool23(
    const __hip_bfloat16* __restrict__ c1,
    __hip_bfloat16* __restrict__ c2,
    __hip_bfloat16* __restrict__ c3) {
    __shared__ float sm[256];
    const int bp  = blockIdx.x;        // 0..8191
    const int tid = threadIdx.x;       // 256 = one c2 element each
    const int y2 = tid >> 4, x2 = tid & 15;
    const __hip_bfloat16* src = c1 + (size_t)bp * 1024 + (2 * y2) * 32 + 2 * x2;
    const float v = (__bfloat162float(src[0]) + __bfloat162float(src[1]) +
                     __bfloat162float(src[32]) + __bfloat162float(src[33])) * 0.25f;
    c2[(size_t)bp * 256 + tid] = __float2bfloat16(v);
    sm[tid] = v;
    __syncthreads();
    if (tid < 64) {
        const int y3 = tid >> 3, x3 = tid & 7;
        const float* r0 = sm + (2 * y3) * 16 + 2 * x3;
        const float w = (r0[0] + r0[1] + r0[16] + r0[17]) * 0.25f;
        c3[(size_t)bp * 64 + tid] = __float2bfloat16(w);
    }
}

// ---------------------------------------------------------------------------
// Gather v2: one wave per (b, n, p) query. Key identity: offsets are
// integers, so floor(x + k) = floor(x) + k -> all 81 samples of a level
// share one bilinear fraction (wx, wy). Load the 10x10 patch (zero-filled
// at borders) into per-wave LDS, then 81 outputs = 4 FMAs each, no
// validity checks needed. 4 waves/block = the 4 n's of one (b,p) ->
// they share the same corr rows (L1 reuse).
// ---------------------------------------------------------------------------
__global__ __launch_bounds__(256) void gather2(
    const float* __restrict__ coords,
    const __hip_bfloat16* __restrict__ c0,
    const __hip_bfloat16* __restrict__ c1,
    const __hip_bfloat16* __restrict__ c2,
    const __hip_bfloat16* __restrict__ c3,
    float* __restrict__ out) {
    __shared__ float patch[4][110];    // per wave: 10 rows x 11 (pad)
    const int tid  = threadIdx.x;
    const int lane = tid & 63;
    const int n    = tid >> 6;         // wave = n
    const int bp   = blockIdx.x;       // 0..8191
    const int b    = bp >> 12;
    const int p    = bp & (P_ - 1);

    const float cx = coords[((size_t)((b * N_ + n) * 2 + 0)) * P_ + p];
    const float cy = coords[((size_t)((b * N_ + n) * 2 + 1)) * P_ + p];
    float* pw = patch[n];
    const size_t obase = ((size_t)(b * N_ + n) * P_ + p) * CTOT;

    #pragma unroll
    for (int lvl = 0; lvl < 4; ++lvl) {
        const __hip_bfloat16* corr =
            (lvl == 0) ? c0 : (lvl == 1) ? c1 : (lvl == 2) ? c2 : c3;
        const int hw = H_ >> lvl;
        const float inv = 1.0f / (float)(1 << lvl);
        const float x = cx * inv, y = cy * inv;
        const float x0f = floorf(x), y0f = floorf(y);
        const int x0 = (int)x0f, y0 = (int)y0f;
        const float wx = x - x0f, wy = y - y0f;
        const __hip_bfloat16* src = corr + (size_t)(b * P_ + p) * (hw * hw);

        __syncthreads();   // WAR: prev level's reads done before overwrite
        #pragma unroll
        for (int it = 0; it < 2; ++it) {
            const int idx = lane + it * 64;
            if (idx < 100) {
                const int r  = idx / 10;        // const-div -> magic mul
                const int cc = idx - r * 10;
                const int gr = y0 - RAD + r;
                const int gc = x0 - RAD + cc;
                const bool ok = (gr >= 0) & (gr < hw) & (gc >= 0) & (gc < hw);
                float v = 0.f;
                if (ok) v = __bfloat162float(src[gr * hw + gc]);
                pw[r * 11 + cc] = v;
            }
        }
        __syncthreads();

        const float omy = 1.f - wy, omx = 1.f - wx;
        const float w00 = omy * omx, w01 = omy * wx;
        const float w10 = wy * omx,  w11 = wy * wx;
        #pragma unroll
        for (int it = 0; it < 2; ++it) {
            const int k2 = lane + it * 64;
            if (k2 < K2_) {
                const int ki = k2 / 9;          // added to x -> patch col
                const int kj = k2 - ki * 9;     // added to y -> patch row
                const float* pr = pw + kj * 11 + ki;
                const float v = w00 * pr[0] + w01 * pr[1] +
                                w10 * pr[11] + w11 * pr[12];
                out[obase + lvl * K2_ + k2] = v;
            }
        }
    }
}

// ---------------------------------------------------------------------------
extern "C" void kernel_launch(void* const* d_in, const int* in_sizes, int n_in,
                              void* d_out, int out_size, void* d_ws, size_t ws_size,
                              hipStream_t stream) {
    const float* fmap1  = (const float*)d_in[0];
    const float* fmap2  = (const float*)d_in[1];
    const float* coords = (const float*)d_in[2];
    float* out = (float*)d_out;

    char* ws = (char*)d_ws;
    __hip_bfloat16* f1t = (__hip_bfloat16*)ws;                    //  4,194,304 B
    __hip_bfloat16* f2t = (__hip_bfloat16*)(ws + 4194304);        //  4,194,304 B
    __hip_bfloat16* c0  = (__hip_bfloat16*)(ws + 8388608);        // 67,108,864 B
    __hip_bfloat16* c1  = (__hip_bfloat16*)(ws + 75497472);       // 16,777,216 B
    __hip_bfloat16* c2  = (__hip_bfloat16*)(ws + 92274688);       //  4,194,304 B
    __hip_bfloat16* c3  = (__hip_bfloat16*)(ws + 96468992);       //  1,048,576 B

    // 1) transpose+convert fmaps to (B, P, C) bf16
    {
        dim3 grid(P_ / 32, C_ / 32, B_);
        dim3 blk(32, 8);
        transpose_cvt<<<grid, blk, 0, stream>>>(fmap1, f1t);
        transpose_cvt<<<grid, blk, 0, stream>>>(fmap2, f2t);
    }

    // 2) all-pairs correlation (level 0) + fused level-1 pooling
    {
        dim3 grid(P_ / 128, P_ / 128, B_);
        gemm_corr<<<grid, 256, 0, stream>>>((const short*)f1t, (const short*)f2t,
                                            c0, c1);
    }

    // 3) pyramid levels 2,3
    pool23<<<B_ * P_, 256, 0, stream>>>(c1, c2, c3);

    // 4) bilinear gather -> output
    gather2<<<B_ * P_, 256, 0, stream>>>(coords, c0, c1, c2, c3, out);
}

// Round 3
// 126.999 us; speedup vs baseline: 1.3928x; 1.0519x over previous
//
#include <hip/hip_runtime.h>
#include <hip/hip_bf16.h>
#include <cstdint>

#define B_    2
#define C_    256
#define H_    64
#define W_    64
#define P_    (H_*W_)      // 4096
#define N_    4
#define RAD   4
#define K2_   81
#define CTOT  (4*K2_)      // 324

typedef __bf16 bf16x8 __attribute__((ext_vector_type(8)));
typedef float  f32x4  __attribute__((ext_vector_type(4)));

__device__ __forceinline__ void gload_lds16(const void* g, void* l) {
    __builtin_amdgcn_global_load_lds(
        (const __attribute__((address_space(1))) void*)g,
        (__attribute__((address_space(3))) void*)l,
        16, 0, 0);
}

// ---------------------------------------------------------------------------
// Transpose + convert, both maps in one dispatch:
// in (B, C, P) fp32  ->  out (B, P, C) bf16
// ---------------------------------------------------------------------------
__global__ void transpose_cvt(const float* __restrict__ in0,
                              const float* __restrict__ in1,
                              __hip_bfloat16* __restrict__ out0,
                              __hip_bfloat16* __restrict__ out1) {
    __shared__ float tile[32][33];
    const int z     = blockIdx.z;
    const int which = z >> 1;
    const int b     = z & 1;
    const float* in          = which ? in1  : in0;
    __hip_bfloat16* out      = which ? out1 : out0;
    const int p0 = blockIdx.x * 32;
    const int c0 = blockIdx.y * 32;
    const int tx = threadIdx.x;   // 0..31
    const int ty = threadIdx.y;   // 0..7
    const float* src = in + ((size_t)b * C_ + c0) * P_ + p0;
    #pragma unroll
    for (int i = 0; i < 32; i += 8)
        tile[ty + i][tx] = src[(size_t)(ty + i) * P_ + tx];   // tile[c][p]
    __syncthreads();
    __hip_bfloat16* dst = out + ((size_t)b * P_ + p0) * C_ + c0;
    #pragma unroll
    for (int i = 0; i < 32; i += 8)
        dst[(size_t)(ty + i) * C_ + tx] = __float2bfloat16(tile[tx][ty + i]);
}

// ---------------------------------------------------------------------------
// Batched GEMM with fused level-1 pooling (unchanged from R2, validated).
// ---------------------------------------------------------------------------
#define TSTR 136   // tile stride in shorts (272 B -> 16B-aligned rows)

__global__ __launch_bounds__(256) void gemm_corr(
    const short* __restrict__ f1t,   // (B, 4096, 256) bf16 bits
    const short* __restrict__ f2t,   // (B, 4096, 256) bf16 bits
    __hip_bfloat16* __restrict__ corr0,  // (B, 4096, 64, 64) bf16
    __hip_bfloat16* __restrict__ corr1)  // (B, 4096, 32, 32) bf16
{
    __shared__ short smem[128 * TSTR];   // 17408 shorts
    short* As = smem;                    // 128*64
    short* Bs = smem + 8192;             // 128*64

    const int tid  = threadIdx.x;
    const int lane = tid & 63;
    const int wv   = tid >> 6;
    const int wm   = (wv >> 1) * 64;
    const int wn   = (wv & 1) * 64;
    const int b    = blockIdx.z;
    const int bx   = blockIdx.x;
    const int m0   = blockIdx.y * 128;
    const int n0   = bx * 128;
    const int qd   = lane >> 4;
    const int l15  = lane & 15;

    const short* gA[4];
    const short* gB[4];
    int ldsOff[4];
    #pragma unroll
    for (int it = 0; it < 4; ++it) {
        const int ci = it * 256 + tid;
        const int r  = ci >> 3;
        const int cp = ci & 7;
        const int kc = cp ^ (r & 7);
        gA[it] = f1t + ((size_t)(b * P_ + m0 + r)) * C_ + kc * 8;
        gB[it] = f2t + ((size_t)(b * P_ + n0 + r)) * C_ + kc * 8;
        ldsOff[it] = (it * 256 + wv * 64) * 8;
    }

    int aAddr[4][2], bAddr[4][2];
    #pragma unroll
    for (int i = 0; i < 4; ++i) {
        const int m = wm + i * 16 + l15;
        const int n = wn + i * 16 + l15;
        #pragma unroll
        for (int s = 0; s < 2; ++s) {
            const int lc = s * 4 + qd;
            aAddr[i][s] = m * 64 + ((lc ^ (m & 7)) * 8);
            bAddr[i][s] = n * 64 + ((lc ^ (n & 7)) * 8);
        }
    }

    f32x4 zero = {0.f, 0.f, 0.f, 0.f};
    f32x4 acc[4][4];
    #pragma unroll
    for (int mi = 0; mi < 4; ++mi)
        #pragma unroll
        for (int ni = 0; ni < 4; ++ni)
            acc[mi][ni] = zero;

    for (int kt = 0; kt < 4; ++kt) {
        const int k0 = kt * 64;
        #pragma unroll
        for (int it = 0; it < 4; ++it) {
            gload_lds16(gA[it] + k0, As + ldsOff[it]);
            gload_lds16(gB[it] + k0, Bs + ldsOff[it]);
        }
        __syncthreads();
        #pragma unroll
        for (int s = 0; s < 2; ++s) {
            bf16x8 af[4], bfr[4];
            #pragma unroll
            for (int i = 0; i < 4; ++i) {
                af[i]  = *(const bf16x8*)(As + aAddr[i][s]);
                bfr[i] = *(const bf16x8*)(Bs + bAddr[i][s]);
            }
            #pragma unroll
            for (int mi = 0; mi < 4; ++mi)
                #pragma unroll
                for (int ni = 0; ni < 4; ++ni)
                    acc[mi][ni] = __builtin_amdgcn_mfma_f32_16x16x32_bf16(
                        af[mi], bfr[ni], acc[mi][ni], 0, 0, 0);
        }
        __syncthreads();
    }

    const float sc = 0.0625f;   // 1/sqrt(256)
    __hip_bfloat16* tile = (__hip_bfloat16*)smem;
    #pragma unroll
    for (int mi = 0; mi < 4; ++mi) {
        #pragma unroll
        for (int ni = 0; ni < 4; ++ni) {
            #pragma unroll
            for (int r = 0; r < 4; ++r) {
                const int rl = wm + mi * 16 + qd * 4 + r;
                const int cl = wn + ni * 16 + l15;
                tile[rl * TSTR + cl] = __float2bfloat16(acc[mi][ni][r] * sc);
            }
        }
    }
    __syncthreads();

    #pragma unroll
    for (int i = 0; i < 8; ++i) {
        const int cid = i * 256 + tid;
        const int tr  = cid >> 4;
        const int tc  = cid & 15;
        const float4 v = *(const float4*)(smem + tr * TSTR + tc * 8);
        *(float4*)(corr0 + ((size_t)(b * P_ + m0 + tr)) * P_ + n0 + tc * 8) = v;
    }

    #pragma unroll
    for (int i = 0; i < 16; ++i) {
        const int oid = i * 256 + tid;
        const int pr  = oid >> 5;
        const int pc  = oid & 31;
        const uint32_t u0 = *(const uint32_t*)(smem + pr * TSTR + 2 * pc);
        const uint32_t u1 = *(const uint32_t*)(smem + pr * TSTR + 64 + 2 * pc);
        const float a0 = __uint_as_float(u0 << 16);
        const float a1 = __uint_as_float(u0 & 0xffff0000u);
        const float b0 = __uint_as_float(u1 << 16);
        const float b1 = __uint_as_float(u1 & 0xffff0000u);
        corr1[((size_t)(b * P_ + m0 + pr)) * 1024 + bx * 32 + pc] =
            __float2bfloat16((a0 + a1 + b0 + b1) * 0.25f);
    }
}

// ---------------------------------------------------------------------------
// Gather v3: one block per (b,p), one wave per n.
// Phase A: pool c1 -> c2 (16x16) and c3 (8x8) in LDS (fused pool2+pool3;
//          c2/c3 never touch global memory).
// Phase B: each wave fills its private 4-level zero-padded patch region
//          (440 floats: lvl*110 + r*11 + c, 10x10 valid) in ONE unrolled
//          pass -> all global loads in flight together; no barrier needed
//          before Phase C (wave-private LDS, in-order wave LDS ops).
// Phase C: 324 outputs = 4 LDS reads + 4 FMAs each.
// ---------------------------------------------------------------------------
#define SEL4(e, a0, a1, a2, a3) ((e)==0?(a0):(e)==1?(a1):(e)==2?(a2):(a3))

__global__ __launch_bounds__(256) void gather3(
    const float* __restrict__ coords,
    const __hip_bfloat16* __restrict__ c0,
    const __hip_bfloat16* __restrict__ c1,
    float* __restrict__ out) {
    __shared__ float pool_sm[320];     // [0..255] = c2, [256..319] = c3
    __shared__ float patch[4][440];    // per wave: 4 levels x (10 x 11)
    const int tid  = threadIdx.x;
    const int lane = tid & 63;
    const int n    = tid >> 6;
    const int bp   = blockIdx.x;       // 0..8191
    const int b    = bp >> 12;
    const int p    = bp & (P_ - 1);

    const __hip_bfloat16* c0b = c0 + (size_t)bp * 4096;
    const __hip_bfloat16* c1b = c1 + (size_t)bp * 1024;

    // ---- Phase A: pool c1 -> c2, c3 (LDS) ----
    {
        const int y2 = tid >> 4, x2 = tid & 15;
        const uint32_t u0 = *(const uint32_t*)(c1b + (2 * y2) * 32 + 2 * x2);
        const uint32_t u1 = *(const uint32_t*)(c1b + (2 * y2 + 1) * 32 + 2 * x2);
        const float a0 = __uint_as_float(u0 << 16);
        const float a1 = __uint_as_float(u0 & 0xffff0000u);
        const float b0 = __uint_as_float(u1 << 16);
        const float b1 = __uint_as_float(u1 & 0xffff0000u);
        pool_sm[tid] = (a0 + a1 + b0 + b1) * 0.25f;
    }
    __syncthreads();
    if (tid < 64) {
        const int y3 = tid >> 3, x3 = tid & 7;
        const float* r0 = pool_sm + (2 * y3) * 16 + 2 * x3;
        pool_sm[256 + tid] = (r0[0] + r0[1] + r0[16] + r0[17]) * 0.25f;
    }
    __syncthreads();

    // ---- per-(n) query geometry, all 4 levels ----
    const float cx = coords[((size_t)((b * N_ + n) * 2 + 0)) * P_ + p];
    const float cy = coords[((size_t)((b * N_ + n) * 2 + 1)) * P_ + p];

    int x0i[4], y0i[4];
    float w00[4], w01[4], w10[4], w11[4];
    #pragma unroll
    for (int l = 0; l < 4; ++l) {
        const float inv = 1.0f / (float)(1 << l);
        const float x = cx * inv, y = cy * inv;
        const float x0f = floorf(x), y0f = floorf(y);
        const float wx = x - x0f, wy = y - y0f;
        x0i[l] = (int)x0f - RAD;
        y0i[l] = (int)y0f - RAD;
        w00[l] = (1.f - wy) * (1.f - wx);
        w01[l] = (1.f - wy) * wx;
        w10[l] = wy * (1.f - wx);
        w11[l] = wy * wx;
    }

    float* pw = patch[n];

    // ---- Phase B: fill all 4 level patches, one pass ----
    #pragma unroll
    for (int it = 0; it < 7; ++it) {
        const int idx = it * 64 + lane;
        if (idx < 440) {
            const int lvl = idx / 110;
            const int rem = idx - lvl * 110;
            const int r   = rem / 11;
            const int cc  = rem - r * 11;
            if (cc < 10) {
                const int hw = H_ >> lvl;
                const int gr = SEL4(lvl, y0i[0], y0i[1], y0i[2], y0i[3]) + r;
                const int gc = SEL4(lvl, x0i[0], x0i[1], x0i[2], x0i[3]) + cc;
                const bool ok = (gr >= 0) & (gr < hw) & (gc >= 0) & (gc < hw);
                float v = 0.f;
                if (ok) {
                    if (lvl < 2) {
                        const __hip_bfloat16* cp = (lvl == 0) ? c0b : c1b;
                        v = __bfloat162float(cp[gr * hw + gc]);
                    } else {
                        const int li = (lvl == 2) ? (gr * 16 + gc)
                                                  : (256 + gr * 8 + gc);
                        v = pool_sm[li];
                    }
                }
                pw[idx] = v;   // idx == lvl*110 + r*11 + cc
            }
        }
    }
    // no barrier: patch[n] is wave-private, wave LDS ops are in-order

    // ---- Phase C: 324 outputs ----
    const size_t obase = ((size_t)(b * N_ + n) * P_ + p) * CTOT;
    #pragma unroll
    for (int it = 0; it < 6; ++it) {
        const int o = it * 64 + lane;
        if (o < CTOT) {
            const int lvl = o / K2_;
            const int k2  = o - lvl * K2_;
            const int ki  = k2 / 9;        // added to x -> patch col
            const int kj  = k2 - ki * 9;   // added to y -> patch row
            const float* pr = pw + lvl * 110 + kj * 11 + ki;
            const float a = SEL4(lvl, w00[0], w00[1], w00[2], w00[3]);
            const float bq = SEL4(lvl, w01[0], w01[1], w01[2], w01[3]);
            const float c = SEL4(lvl, w10[0], w10[1], w10[2], w10[3]);
            const float d = SEL4(lvl, w11[0], w11[1], w11[2], w11[3]);
            out[obase + o] = a * pr[0] + bq * pr[1] + c * pr[11] + d * pr[12];
        }
    }
}

// ---------------------------------------------------------------------------
extern "C" void kernel_launch(void* const* d_in, const int* in_sizes, int n_in,
                              void* d_out, int out_size, void* d_ws, size_t ws_size,
                              hipStream_t stream) {
    const float* fmap1  = (const float*)d_in[0];
    const float* fmap2  = (const float*)d_in[1];
    const float* coords = (const float*)d_in[2];
    float* out = (float*)d_out;

    char* ws = (char*)d_ws;
    __hip_bfloat16* f1t = (__hip_bfloat16*)ws;                    //  4,194,304 B
    __hip_bfloat16* f2t = (__hip_bfloat16*)(ws + 4194304);        //  4,194,304 B
    __hip_bfloat16* c0  = (__hip_bfloat16*)(ws + 8388608);        // 67,108,864 B
    __hip_bfloat16* c1  = (__hip_bfloat16*)(ws + 75497472);       // 16,777,216 B

    // 1) transpose+convert both fmaps (one dispatch)
    {
        dim3 grid(P_ / 32, C_ / 32, 2 * B_);
        dim3 blk(32, 8);
        transpose_cvt<<<grid, blk, 0, stream>>>(fmap1, fmap2, f1t, f2t);
    }

    // 2) all-pairs correlation (level 0) + fused level-1 pooling
    {
        dim3 grid(P_ / 128, P_ / 128, B_);
        gemm_corr<<<grid, 256, 0, stream>>>((const short*)f1t, (const short*)f2t,
                                            c0, c1);
    }

    // 3) fused pool2+pool3 + 4-level bilinear gather
    gather3<<<B_ * P_, 256, 0, stream>>>(coords, c0, c1, out);
}